// Round 1
// baseline (468.678 us; speedup 1.0000x reference)
//
#include <hip/hip_runtime.h>
#include <math.h>

// R0: correctness-first full fp32 GAT pipeline.
// Pipeline: GEMM1 -> scores1 -> CSR build (count/scan/fill) -> agg1(softmax+aggregate+bias+relu)
//           -> GEMM2 -> scores2 -> agg2 -> attention pool -> final tiny GEMM.
// Self-loops handled implicitly in agg kernels (not stored in CSR).

#define NEG_SLOPE 0.2f

// ---------------- GEMM: C[M,N] = A[M,K] * B[N,K]^T ----------------
// 64x64 tile, 256 threads, 4x4 per thread, K-chunk 32.
__global__ __launch_bounds__(256) void gemm_nt(const float* __restrict__ A,
                                               const float* __restrict__ B,
                                               float* __restrict__ C,
                                               int M, int N, int K) {
    __shared__ float As[32][68];   // [k][m], pad 68 keeps float4 alignment
    __shared__ float Bs[32][68];   // [k][n]
    int t = threadIdx.x;
    int m0 = blockIdx.x * 64;
    int n0 = blockIdx.y * 64;
    int tx = t & 15, ty = t >> 4;
    int kload = t & 31;            // k within chunk
    int mload = (t >> 5) * 8;      // 8 rows per thread
    float acc[4][4] = {};
    for (int k0 = 0; k0 < K; k0 += 32) {
        float av[8], bv[8];
#pragma unroll
        for (int j = 0; j < 8; ++j) {
            int row = m0 + mload + j;
            av[j] = (row < M) ? A[(size_t)row * K + k0 + kload] : 0.0f;
            bv[j] = B[(size_t)(n0 + mload + j) * K + k0 + kload];  // N tiles exact
        }
        __syncthreads();   // previous chunk's readers done
#pragma unroll
        for (int j = 0; j < 8; ++j) {
            As[kload][mload + j] = av[j];
            Bs[kload][mload + j] = bv[j];
        }
        __syncthreads();
#pragma unroll
        for (int k = 0; k < 32; ++k) {
            float4 a4 = *(const float4*)&As[k][ty * 4];
            float4 b4 = *(const float4*)&Bs[k][tx * 4];
            float a[4] = {a4.x, a4.y, a4.z, a4.w};
            float b[4] = {b4.x, b4.y, b4.z, b4.w};
#pragma unroll
            for (int i = 0; i < 4; ++i)
#pragma unroll
                for (int j = 0; j < 4; ++j) acc[i][j] += a[i] * b[j];
        }
    }
#pragma unroll
    for (int i = 0; i < 4; ++i) {
        int row = m0 + ty * 4 + i;
        if (row < M) {
            float4 v = make_float4(acc[i][0], acc[i][1], acc[i][2], acc[i][3]);
            *(float4*)&C[(size_t)row * N + n0 + tx * 4] = v;
        }
    }
}

// ---------------- Layer-1 attention scores: a1s/a1d [N,8] ----------------
__global__ __launch_bounds__(256) void scores1(const float* __restrict__ h1,
                                               const float* __restrict__ att_s,
                                               const float* __restrict__ att_d,
                                               float* __restrict__ a1s,
                                               float* __restrict__ a1d, int N) {
    int node = blockIdx.x * 4 + (threadIdx.x >> 6);
    if (node >= N) return;
    int lane = threadIdx.x & 63;
    const float4* hp = (const float4*)(h1 + (size_t)node * 512 + lane * 8);
    float4 h0 = hp[0], h1v = hp[1];
    const float4* sp = (const float4*)(att_s + lane * 8);
    const float4* dp = (const float4*)(att_d + lane * 8);
    float4 s0 = sp[0], s1 = sp[1], d0 = dp[0], d1 = dp[1];
    float ps = h0.x * s0.x + h0.y * s0.y + h0.z * s0.z + h0.w * s0.w +
               h1v.x * s1.x + h1v.y * s1.y + h1v.z * s1.z + h1v.w * s1.w;
    float pd = h0.x * d0.x + h0.y * d0.y + h0.z * d0.z + h0.w * d0.w +
               h1v.x * d1.x + h1v.y * d1.y + h1v.z * d1.z + h1v.w * d1.w;
#pragma unroll
    for (int off = 1; off < 8; off <<= 1) {
        ps += __shfl_xor(ps, off);
        pd += __shfl_xor(pd, off);
    }
    if ((lane & 7) == 0) {
        a1s[node * 8 + (lane >> 3)] = ps;
        a1d[node * 8 + (lane >> 3)] = pd;
    }
}

// ---------------- CSR build ----------------
__global__ void count_edges(const int* __restrict__ dst, int* cnt, int E) {
    int e = blockIdx.x * 256 + threadIdx.x;
    if (e < E) atomicAdd(&cnt[dst[e]], 1);
}

// single block; cnt may alias cursor
__global__ __launch_bounds__(1024) void scan_offsets(const int* cnt, int* row_start,
                                                     int* cursor, int N) {
    __shared__ int sm[1024];
    int t = threadIdx.x;
    int per = (N + 1023) / 1024;
    int beg = t * per;
    int end = beg + per; if (end > N) end = N;
    int sum = 0;
    for (int i = beg; i < end; ++i) sum += cnt[i];
    sm[t] = sum;
    __syncthreads();
    for (int off = 1; off < 1024; off <<= 1) {
        int add = (t >= off) ? sm[t - off] : 0;
        __syncthreads();
        sm[t] += add;
        __syncthreads();
    }
    int run = sm[t] - sum;  // exclusive prefix for this thread's chunk
    for (int i = beg; i < end; ++i) {
        int c = cnt[i];          // read before cursor[i] overwrite (may alias)
        row_start[i] = run;
        cursor[i] = run;
        run += c;
    }
    if (t == 1023) row_start[N] = run;
}

__global__ void fill_edges(const int* __restrict__ src, const int* __restrict__ dst,
                           int* cursor, int* __restrict__ srcs, int E) {
    int e = blockIdx.x * 256 + threadIdx.x;
    if (e < E) {
        int pos = atomicAdd(&cursor[dst[e]], 1);
        srcs[pos] = src[e];
    }
}

// ---------------- Layer-1 softmax + aggregate + bias + relu ----------------
// one wave per node; lane covers 8 features (one head = lanes 8h..8h+7)
__global__ __launch_bounds__(256) void agg1(const float* __restrict__ h1,
                                            const float* __restrict__ a1s,
                                            const float* __restrict__ a1d,
                                            const int* __restrict__ row_start,
                                            const int* __restrict__ srcs,
                                            const float* __restrict__ b1,
                                            float* __restrict__ r1, int N) {
    int node = blockIdx.x * 4 + (threadIdx.x >> 6);
    if (node >= N) return;
    int lane = threadIdx.x & 63;
    int head = lane >> 3;
    int f0 = lane * 8;
    int pbeg = row_start[node], pend = row_start[node + 1];
    float ad = a1d[node * 8 + head];
    // self loop
    float es = a1s[node * 8 + head] + ad;
    es = es > 0.f ? es : NEG_SLOPE * es;
    float ex_self = expf(es);
    float den = ex_self;
    for (int p = pbeg; p < pend; ++p) {
        int s = srcs[p];
        float e = a1s[s * 8 + head] + ad;
        e = e > 0.f ? e : NEG_SLOPE * e;
        den += expf(e);
    }
    float rden = 1.0f / (den + 1e-16f);
    const float4* hs = (const float4*)(h1 + (size_t)node * 512 + f0);
    float4 q0 = hs[0], q1 = hs[1];
    float a0 = ex_self * rden;
    float acc[8] = {a0 * q0.x, a0 * q0.y, a0 * q0.z, a0 * q0.w,
                    a0 * q1.x, a0 * q1.y, a0 * q1.z, a0 * q1.w};
    for (int p = pbeg; p < pend; ++p) {
        int s = srcs[p];
        float e = a1s[s * 8 + head] + ad;
        e = e > 0.f ? e : NEG_SLOPE * e;
        float alpha = expf(e) * rden;
        const float4* hp = (const float4*)(h1 + (size_t)s * 512 + f0);
        float4 v0 = hp[0], v1 = hp[1];
        acc[0] += alpha * v0.x; acc[1] += alpha * v0.y;
        acc[2] += alpha * v0.z; acc[3] += alpha * v0.w;
        acc[4] += alpha * v1.x; acc[5] += alpha * v1.y;
        acc[6] += alpha * v1.z; acc[7] += alpha * v1.w;
    }
    const float4* bp = (const float4*)(b1 + f0);
    float4 b0 = bp[0], b1v = bp[1];
    float4 o0 = make_float4(fmaxf(acc[0] + b0.x, 0.f), fmaxf(acc[1] + b0.y, 0.f),
                            fmaxf(acc[2] + b0.z, 0.f), fmaxf(acc[3] + b0.w, 0.f));
    float4 o1 = make_float4(fmaxf(acc[4] + b1v.x, 0.f), fmaxf(acc[5] + b1v.y, 0.f),
                            fmaxf(acc[6] + b1v.z, 0.f), fmaxf(acc[7] + b1v.w, 0.f));
    float4* op = (float4*)(r1 + (size_t)node * 512 + f0);
    op[0] = o0; op[1] = o1;
}

// ---------------- Layer-2 attention scores (H=1, C=128) ----------------
__global__ __launch_bounds__(256) void scores2(const float* __restrict__ h2,
                                               const float* __restrict__ att_s,
                                               const float* __restrict__ att_d,
                                               float* __restrict__ a2s,
                                               float* __restrict__ a2d, int N) {
    int node = blockIdx.x * 4 + (threadIdx.x >> 6);
    if (node >= N) return;
    int lane = threadIdx.x & 63;
    float2 h = *(const float2*)(h2 + (size_t)node * 128 + lane * 2);
    float2 s = *(const float2*)(att_s + lane * 2);
    float2 d = *(const float2*)(att_d + lane * 2);
    float ps = h.x * s.x + h.y * s.y;
    float pd = h.x * d.x + h.y * d.y;
#pragma unroll
    for (int off = 1; off < 64; off <<= 1) {
        ps += __shfl_xor(ps, off);
        pd += __shfl_xor(pd, off);
    }
    if (lane == 0) { a2s[node] = ps; a2d[node] = pd; }
}

// ---------------- Layer-2 softmax + aggregate + bias + relu ----------------
__global__ __launch_bounds__(256) void agg2(const float* __restrict__ h2,
                                            const float* __restrict__ a2s,
                                            const float* __restrict__ a2d,
                                            const int* __restrict__ row_start,
                                            const int* __restrict__ srcs,
                                            const float* __restrict__ b2,
                                            float* __restrict__ r2, int N) {
    int node = blockIdx.x * 4 + (threadIdx.x >> 6);
    if (node >= N) return;
    int lane = threadIdx.x & 63;
    int f0 = lane * 2;
    int pbeg = row_start[node], pend = row_start[node + 1];
    float ad = a2d[node];
    float es = a2s[node] + ad;
    es = es > 0.f ? es : NEG_SLOPE * es;
    float ex_self = expf(es);
    float den = ex_self;
    for (int p = pbeg; p < pend; ++p) {
        float e = a2s[srcs[p]] + ad;
        e = e > 0.f ? e : NEG_SLOPE * e;
        den += expf(e);
    }
    float rden = 1.0f / (den + 1e-16f);
    float2 hv = *(const float2*)(h2 + (size_t)node * 128 + f0);
    float a0 = ex_self * rden;
    float acc0 = a0 * hv.x, acc1 = a0 * hv.y;
    for (int p = pbeg; p < pend; ++p) {
        int s = srcs[p];
        float e = a2s[s] + ad;
        e = e > 0.f ? e : NEG_SLOPE * e;
        float alpha = expf(e) * rden;
        float2 q = *(const float2*)(h2 + (size_t)s * 128 + f0);
        acc0 += alpha * q.x;
        acc1 += alpha * q.y;
    }
    acc0 = fmaxf(acc0 + b2[f0], 0.f);
    acc1 = fmaxf(acc1 + b2[f0 + 1], 0.f);
    *(float2*)(r2 + (size_t)node * 128 + f0) = make_float2(acc0, acc1);
}

// ---------------- Attention pooling ----------------
__global__ __launch_bounds__(256) void pool_kernel(const float* __restrict__ r2,
                                                   const int* __restrict__ batch,
                                                   const float* __restrict__ w_attn,
                                                   const float* __restrict__ b_attn,
                                                   const float* __restrict__ w_mask,
                                                   const float* __restrict__ b_mask,
                                                   float* pooled, int N) {
    int node = blockIdx.x * 4 + (threadIdx.x >> 6);
    if (node >= N) return;
    int lane = threadIdx.x & 63;
    float2 h = *(const float2*)(r2 + (size_t)node * 128 + lane * 2);
    float2 wa = *(const float2*)(w_attn + lane * 2);
    float2 wm = *(const float2*)(w_mask + lane * 2);
    float pa = h.x * wa.x + h.y * wa.y;
    float pm = h.x * wm.x + h.y * wm.y;
#pragma unroll
    for (int off = 1; off < 64; off <<= 1) {
        pa += __shfl_xor(pa, off);
        pm += __shfl_xor(pm, off);
    }
    float attn = pa + b_attn[0];
    float mask = 1.0f / (1.0f + expf(-(pm + b_mask[0])));
    float w = attn * mask;
    int g = batch[node];
    atomicAdd(&pooled[g * 128 + lane * 2], h.x * w);
    atomicAdd(&pooled[g * 128 + lane * 2 + 1], h.y * w);
}

// ---------------- Final tiny GEMM: out[256,2] ----------------
__global__ void final_kernel(const float* __restrict__ pooled,
                             const float* __restrict__ W_out,
                             const float* __restrict__ b_out,
                             float* __restrict__ out) {
    int tid = blockIdx.x * 256 + threadIdx.x;
    if (tid >= 512) return;
    int g = tid >> 1, o = tid & 1;
    const float* p = pooled + g * 128;
    const float* w = W_out + o * 128;
    float s = 0.f;
#pragma unroll 4
    for (int f = 0; f < 128; ++f) s += p[f] * w[f];
    out[tid] = s + b_out[o];
}

extern "C" void kernel_launch(void* const* d_in, const int* in_sizes, int n_in,
                              void* d_out, int out_size, void* d_ws, size_t ws_size,
                              hipStream_t stream) {
    const float* x        = (const float*)d_in[0];
    const int* edge_index = (const int*)d_in[1];
    const int* batch      = (const int*)d_in[2];
    const float* W1       = (const float*)d_in[3];
    const float* att_src1 = (const float*)d_in[4];
    const float* att_dst1 = (const float*)d_in[5];
    const float* b1       = (const float*)d_in[6];
    const float* W2       = (const float*)d_in[7];
    const float* att_src2 = (const float*)d_in[8];
    const float* att_dst2 = (const float*)d_in[9];
    const float* b2       = (const float*)d_in[10];
    const float* w_attn   = (const float*)d_in[11];
    const float* b_attn   = (const float*)d_in[12];
    const float* w_mask   = (const float*)d_in[13];
    const float* b_mask   = (const float*)d_in[14];
    const float* W_out    = (const float*)d_in[15];
    const float* b_out    = (const float*)d_in[16];
    float* out = (float*)d_out;

    int N = in_sizes[0] / 128;
    int E = in_sizes[1] / 2;
    const int* esrc = edge_index;
    const int* edst = edge_index + E;

    char* ws = (char*)d_ws;
    size_t off = 0;
    auto alloc = [&](size_t bytes) {
        void* p = ws + off;
        off = (off + bytes + 255) & ~(size_t)255;
        return p;
    };
    float* h1        = (float*)alloc((size_t)N * 512 * 4);  // reused: h2 then dead
    float* r1        = (float*)alloc((size_t)N * 512 * 4);
    float* a1s       = (float*)alloc((size_t)N * 8 * 4);
    float* a1d       = (float*)alloc((size_t)N * 8 * 4);
    float* a2s       = (float*)alloc((size_t)N * 4);
    float* a2d       = (float*)alloc((size_t)N * 4);
    int*   row_start = (int*)alloc((size_t)(N + 1) * 4);
    int*   cursor    = (int*)alloc((size_t)N * 4);
    int*   srcs      = (int*)alloc((size_t)E * 4);
    float* pooled    = (float*)alloc((size_t)256 * 128 * 4);
    // alias h2/r2 into the dead h1 region (h1 unused after agg1/gemm2 staging)
    float* h2 = h1;                       // [N,128] written by gemm2 (reads only r1)
    float* r2 = h1 + (size_t)N * 128;     // [N,128] disjoint from h2

    hipMemsetAsync(cursor, 0, (size_t)N * 4, stream);
    hipMemsetAsync(pooled, 0, 256 * 128 * 4, stream);

    dim3 b256(256);
    gemm_nt<<<dim3((N + 63) / 64, 512 / 64), b256, 0, stream>>>(x, W1, h1, N, 512, 128);
    scores1<<<(N + 3) / 4, b256, 0, stream>>>(h1, att_src1, att_dst1, a1s, a1d, N);
    count_edges<<<(E + 255) / 256, b256, 0, stream>>>(edst, cursor, E);
    scan_offsets<<<1, 1024, 0, stream>>>(cursor, row_start, cursor, N);
    fill_edges<<<(E + 255) / 256, b256, 0, stream>>>(esrc, edst, cursor, srcs, E);
    agg1<<<(N + 3) / 4, b256, 0, stream>>>(h1, a1s, a1d, row_start, srcs, b1, r1, N);
    gemm_nt<<<dim3((N + 63) / 64, 128 / 64), b256, 0, stream>>>(r1, W2, h2, N, 128, 512);
    scores2<<<(N + 3) / 4, b256, 0, stream>>>(h2, att_src2, att_dst2, a2s, a2d, N);
    agg2<<<(N + 3) / 4, b256, 0, stream>>>(h2, a2s, a2d, row_start, srcs, b2, r2, N);
    pool_kernel<<<(N + 3) / 4, b256, 0, stream>>>(r2, batch, w_attn, b_attn, w_mask,
                                                  b_mask, pooled, N);
    final_kernel<<<2, b256, 0, stream>>>(pooled, W_out, b_out, out);
}

// Round 2
// 394.300 us; speedup vs baseline: 1.1886x; 1.1886x over previous
//
#include <hip/hip_runtime.h>
#include <math.h>

// R1: bf16 intermediates (h1, r1, h2) + single-pass softmax-aggregate.
// Pipeline: GEMM1(fp32 in, bf16 out) -> scores1 -> CSR build -> agg1(single-pass)
//           -> GEMM2(bf16 A, bf16 out) -> scores2 -> agg2(half-wave) -> pool -> final.
// fp32 accumulation everywhere; tolerance is 2% of ref absmax (bf16-grade).

#define NEG_SLOPE 0.2f

// ---------- bf16 helpers (storage ushort, fp32 compute) ----------
__device__ __forceinline__ float bf2f(ushort u) {
    return __uint_as_float(((unsigned)u) << 16);
}
__device__ __forceinline__ ushort f2bf(float f) {
    unsigned u = __float_as_uint(f);
    unsigned r = (u + 0x7FFFu + ((u >> 16) & 1u)) >> 16;   // RNE
    return (ushort)r;
}
__device__ __forceinline__ unsigned pack2(float a, float b) {
    return (unsigned)f2bf(a) | ((unsigned)f2bf(b) << 16);
}
__device__ __forceinline__ void unpack8(uint4 u, float* f) {
    f[0] = __uint_as_float(u.x << 16); f[1] = __uint_as_float(u.x & 0xFFFF0000u);
    f[2] = __uint_as_float(u.y << 16); f[3] = __uint_as_float(u.y & 0xFFFF0000u);
    f[4] = __uint_as_float(u.z << 16); f[5] = __uint_as_float(u.z & 0xFFFF0000u);
    f[6] = __uint_as_float(u.w << 16); f[7] = __uint_as_float(u.w & 0xFFFF0000u);
}
__device__ __forceinline__ void unpack4(uint2 u, float* f) {
    f[0] = __uint_as_float(u.x << 16); f[1] = __uint_as_float(u.x & 0xFFFF0000u);
    f[2] = __uint_as_float(u.y << 16); f[3] = __uint_as_float(u.y & 0xFFFF0000u);
}

__device__ __forceinline__ float loadA(float v) { return v; }
__device__ __forceinline__ float loadA(ushort v) { return bf2f(v); }

// ---------------- GEMM: C[M,N] = A[M,K] * B[N,K]^T, C stored bf16 ----------------
// 64x64 tile, 256 threads, 4x4 per thread, K-chunk 32. fp32 accumulate.
template <typename TA>
__global__ __launch_bounds__(256) void gemm_nt(const TA* __restrict__ A,
                                               const float* __restrict__ B,
                                               ushort* __restrict__ C,
                                               int M, int N, int K) {
    __shared__ float As[32][68];   // [k][m]
    __shared__ float Bs[32][68];   // [k][n]
    int t = threadIdx.x;
    int m0 = blockIdx.x * 64;
    int n0 = blockIdx.y * 64;
    int tx = t & 15, ty = t >> 4;
    int kload = t & 31;
    int mload = (t >> 5) * 8;
    float acc[4][4] = {};
    for (int k0 = 0; k0 < K; k0 += 32) {
        float av[8], bv[8];
#pragma unroll
        for (int j = 0; j < 8; ++j) {
            int row = m0 + mload + j;
            av[j] = (row < M) ? loadA(A[(size_t)row * K + k0 + kload]) : 0.0f;
            bv[j] = B[(size_t)(n0 + mload + j) * K + k0 + kload];
        }
        __syncthreads();
#pragma unroll
        for (int j = 0; j < 8; ++j) {
            As[kload][mload + j] = av[j];
            Bs[kload][mload + j] = bv[j];
        }
        __syncthreads();
#pragma unroll
        for (int k = 0; k < 32; ++k) {
            float4 a4 = *(const float4*)&As[k][ty * 4];
            float4 b4 = *(const float4*)&Bs[k][tx * 4];
            float a[4] = {a4.x, a4.y, a4.z, a4.w};
            float b[4] = {b4.x, b4.y, b4.z, b4.w};
#pragma unroll
            for (int i = 0; i < 4; ++i)
#pragma unroll
                for (int j = 0; j < 4; ++j) acc[i][j] += a[i] * b[j];
        }
    }
#pragma unroll
    for (int i = 0; i < 4; ++i) {
        int row = m0 + ty * 4 + i;
        if (row < M) {
            uint2 v;
            v.x = pack2(acc[i][0], acc[i][1]);
            v.y = pack2(acc[i][2], acc[i][3]);
            *(uint2*)&C[(size_t)row * N + n0 + tx * 4] = v;
        }
    }
}

// ---------------- Layer-1 attention scores: a1s/a1d [N,8], h1 bf16 ----------------
__global__ __launch_bounds__(256) void scores1(const ushort* __restrict__ h1,
                                               const float* __restrict__ att_s,
                                               const float* __restrict__ att_d,
                                               float* __restrict__ a1s,
                                               float* __restrict__ a1d, int N) {
    int node = blockIdx.x * 4 + (threadIdx.x >> 6);
    if (node >= N) return;
    int lane = threadIdx.x & 63;
    uint4 u = *(const uint4*)(h1 + (size_t)node * 512 + lane * 8);
    float h[8];
    unpack8(u, h);
    const float4* sp = (const float4*)(att_s + lane * 8);
    const float4* dp = (const float4*)(att_d + lane * 8);
    float4 s0 = sp[0], s1 = sp[1], d0 = dp[0], d1 = dp[1];
    float ps = h[0] * s0.x + h[1] * s0.y + h[2] * s0.z + h[3] * s0.w +
               h[4] * s1.x + h[5] * s1.y + h[6] * s1.z + h[7] * s1.w;
    float pd = h[0] * d0.x + h[1] * d0.y + h[2] * d0.z + h[3] * d0.w +
               h[4] * d1.x + h[5] * d1.y + h[6] * d1.z + h[7] * d1.w;
#pragma unroll
    for (int off = 1; off < 8; off <<= 1) {
        ps += __shfl_xor(ps, off);
        pd += __shfl_xor(pd, off);
    }
    if ((lane & 7) == 0) {
        a1s[node * 8 + (lane >> 3)] = ps;
        a1d[node * 8 + (lane >> 3)] = pd;
    }
}

// ---------------- CSR build ----------------
__global__ void count_edges(const int* __restrict__ dst, int* cnt, int E) {
    int e = blockIdx.x * 256 + threadIdx.x;
    if (e < E) atomicAdd(&cnt[dst[e]], 1);
}

__global__ __launch_bounds__(1024) void scan_offsets(const int* cnt, int* row_start,
                                                     int* cursor, int N) {
    __shared__ int sm[1024];
    int t = threadIdx.x;
    int per = (N + 1023) / 1024;
    int beg = t * per;
    int end = beg + per; if (end > N) end = N;
    int sum = 0;
    for (int i = beg; i < end; ++i) sum += cnt[i];
    sm[t] = sum;
    __syncthreads();
    for (int off = 1; off < 1024; off <<= 1) {
        int add = (t >= off) ? sm[t - off] : 0;
        __syncthreads();
        sm[t] += add;
        __syncthreads();
    }
    int run = sm[t] - sum;
    for (int i = beg; i < end; ++i) {
        int c = cnt[i];
        row_start[i] = run;
        cursor[i] = run;
        run += c;
    }
    if (t == 1023) row_start[N] = run;
}

__global__ void fill_edges(const int* __restrict__ src, const int* __restrict__ dst,
                           int* cursor, int* __restrict__ srcs, int E) {
    int e = blockIdx.x * 256 + threadIdx.x;
    if (e < E) {
        int pos = atomicAdd(&cursor[dst[e]], 1);
        srcs[pos] = src[e];
    }
}

// ---------------- Layer-1 single-pass softmax-aggregate + bias + relu ----------------
// one wave per node; lane covers 8 features; head = lane>>3.
// out = (Sigma exp(e)*h[src]) / (Sigma exp(e))  -- no max subtraction (|e| <~ 9).
__global__ __launch_bounds__(256) void agg1(const ushort* __restrict__ h1,
                                            const float* __restrict__ a1s,
                                            const float* __restrict__ a1d,
                                            const int* __restrict__ row_start,
                                            const int* __restrict__ srcs,
                                            const float* __restrict__ b1,
                                            ushort* __restrict__ r1, int N) {
    int node = blockIdx.x * 4 + (threadIdx.x >> 6);
    if (node >= N) return;
    int lane = threadIdx.x & 63;
    int head = lane >> 3;
    int f0 = lane * 8;
    int pbeg = row_start[node], pend = row_start[node + 1];
    float ad = a1d[node * 8 + head];
    // self loop
    float es = a1s[node * 8 + head] + ad;
    es = es > 0.f ? es : NEG_SLOPE * es;
    float ex_self = __expf(es);
    float den = ex_self;
    float q[8];
    unpack8(*(const uint4*)(h1 + (size_t)node * 512 + f0), q);
    float acc[8];
#pragma unroll
    for (int j = 0; j < 8; ++j) acc[j] = ex_self * q[j];
    for (int p = pbeg; p < pend; ++p) {
        int s = srcs[p];
        float e = a1s[s * 8 + head] + ad;
        e = e > 0.f ? e : NEG_SLOPE * e;
        float ex = __expf(e);
        den += ex;
        float v[8];
        unpack8(*(const uint4*)(h1 + (size_t)s * 512 + f0), v);
#pragma unroll
        for (int j = 0; j < 8; ++j) acc[j] += ex * v[j];
    }
    float rden = 1.0f / (den + 1e-16f);
    const float4* bp = (const float4*)(b1 + f0);
    float4 b0 = bp[0], b1v = bp[1];
    float o[8];
    o[0] = fmaxf(acc[0] * rden + b0.x, 0.f);
    o[1] = fmaxf(acc[1] * rden + b0.y, 0.f);
    o[2] = fmaxf(acc[2] * rden + b0.z, 0.f);
    o[3] = fmaxf(acc[3] * rden + b0.w, 0.f);
    o[4] = fmaxf(acc[4] * rden + b1v.x, 0.f);
    o[5] = fmaxf(acc[5] * rden + b1v.y, 0.f);
    o[6] = fmaxf(acc[6] * rden + b1v.z, 0.f);
    o[7] = fmaxf(acc[7] * rden + b1v.w, 0.f);
    uint4 ov;
    ov.x = pack2(o[0], o[1]); ov.y = pack2(o[2], o[3]);
    ov.z = pack2(o[4], o[5]); ov.w = pack2(o[6], o[7]);
    *(uint4*)(r1 + (size_t)node * 512 + f0) = ov;
}

// ---------------- Layer-2 attention scores (H=1, C=128), h2 bf16 ----------------
__global__ __launch_bounds__(256) void scores2(const ushort* __restrict__ h2,
                                               const float* __restrict__ att_s,
                                               const float* __restrict__ att_d,
                                               float* __restrict__ a2s,
                                               float* __restrict__ a2d, int N) {
    int node = blockIdx.x * 4 + (threadIdx.x >> 6);
    if (node >= N) return;
    int lane = threadIdx.x & 63;
    unsigned u = *(const unsigned*)(h2 + (size_t)node * 128 + lane * 2);
    float h0 = __uint_as_float(u << 16), h1v = __uint_as_float(u & 0xFFFF0000u);
    float2 s = *(const float2*)(att_s + lane * 2);
    float2 d = *(const float2*)(att_d + lane * 2);
    float ps = h0 * s.x + h1v * s.y;
    float pd = h0 * d.x + h1v * d.y;
#pragma unroll
    for (int off = 1; off < 64; off <<= 1) {
        ps += __shfl_xor(ps, off);
        pd += __shfl_xor(pd, off);
    }
    if (lane == 0) { a2s[node] = ps; a2d[node] = pd; }
}

// ---------------- Layer-2 single-pass aggregate: 2 nodes per wave ----------------
// 32 lanes per node, 4 features per lane (uint2 = 4 bf16).
__global__ __launch_bounds__(256) void agg2(const ushort* __restrict__ h2,
                                            const float* __restrict__ a2s,
                                            const float* __restrict__ a2d,
                                            const int* __restrict__ row_start,
                                            const int* __restrict__ srcs,
                                            const float* __restrict__ b2,
                                            float* __restrict__ r2, int N) {
    int node = blockIdx.x * 8 + (threadIdx.x >> 5);
    if (node >= N) return;
    int sub = threadIdx.x & 31;
    int f0 = sub * 4;
    int pbeg = row_start[node], pend = row_start[node + 1];
    float ad = a2d[node];
    float es = a2s[node] + ad;
    es = es > 0.f ? es : NEG_SLOPE * es;
    float ex_self = __expf(es);
    float den = ex_self;
    float q[4];
    unpack4(*(const uint2*)(h2 + (size_t)node * 128 + f0), q);
    float acc[4];
#pragma unroll
    for (int j = 0; j < 4; ++j) acc[j] = ex_self * q[j];
    for (int p = pbeg; p < pend; ++p) {
        int s = srcs[p];
        float e = a2s[s] + ad;
        e = e > 0.f ? e : NEG_SLOPE * e;
        float ex = __expf(e);
        den += ex;
        float v[4];
        unpack4(*(const uint2*)(h2 + (size_t)s * 128 + f0), v);
#pragma unroll
        for (int j = 0; j < 4; ++j) acc[j] += ex * v[j];
    }
    float rden = 1.0f / (den + 1e-16f);
    float4 bv = *(const float4*)(b2 + f0);
    float4 o;
    o.x = fmaxf(acc[0] * rden + bv.x, 0.f);
    o.y = fmaxf(acc[1] * rden + bv.y, 0.f);
    o.z = fmaxf(acc[2] * rden + bv.z, 0.f);
    o.w = fmaxf(acc[3] * rden + bv.w, 0.f);
    *(float4*)(r2 + (size_t)node * 128 + f0) = o;
}

// ---------------- Attention pooling ----------------
__global__ __launch_bounds__(256) void pool_kernel(const float* __restrict__ r2,
                                                   const int* __restrict__ batch,
                                                   const float* __restrict__ w_attn,
                                                   const float* __restrict__ b_attn,
                                                   const float* __restrict__ w_mask,
                                                   const float* __restrict__ b_mask,
                                                   float* pooled, int N) {
    int node = blockIdx.x * 4 + (threadIdx.x >> 6);
    if (node >= N) return;
    int lane = threadIdx.x & 63;
    float2 h = *(const float2*)(r2 + (size_t)node * 128 + lane * 2);
    float2 wa = *(const float2*)(w_attn + lane * 2);
    float2 wm = *(const float2*)(w_mask + lane * 2);
    float pa = h.x * wa.x + h.y * wa.y;
    float pm = h.x * wm.x + h.y * wm.y;
#pragma unroll
    for (int off = 1; off < 64; off <<= 1) {
        pa += __shfl_xor(pa, off);
        pm += __shfl_xor(pm, off);
    }
    float attn = pa + b_attn[0];
    float mask = 1.0f / (1.0f + __expf(-(pm + b_mask[0])));
    float w = attn * mask;
    int g = batch[node];
    atomicAdd(&pooled[g * 128 + lane * 2], h.x * w);
    atomicAdd(&pooled[g * 128 + lane * 2 + 1], h.y * w);
}

// ---------------- Final tiny GEMM: out[256,2] ----------------
__global__ void final_kernel(const float* __restrict__ pooled,
                             const float* __restrict__ W_out,
                             const float* __restrict__ b_out,
                             float* __restrict__ out) {
    int tid = blockIdx.x * 256 + threadIdx.x;
    if (tid >= 512) return;
    int g = tid >> 1, o = tid & 1;
    const float* p = pooled + g * 128;
    const float* w = W_out + o * 128;
    float s = 0.f;
#pragma unroll 4
    for (int f = 0; f < 128; ++f) s += p[f] * w[f];
    out[tid] = s + b_out[o];
}

extern "C" void kernel_launch(void* const* d_in, const int* in_sizes, int n_in,
                              void* d_out, int out_size, void* d_ws, size_t ws_size,
                              hipStream_t stream) {
    const float* x        = (const float*)d_in[0];
    const int* edge_index = (const int*)d_in[1];
    const int* batch      = (const int*)d_in[2];
    const float* W1       = (const float*)d_in[3];
    const float* att_src1 = (const float*)d_in[4];
    const float* att_dst1 = (const float*)d_in[5];
    const float* b1       = (const float*)d_in[6];
    const float* W2       = (const float*)d_in[7];
    const float* att_src2 = (const float*)d_in[8];
    const float* att_dst2 = (const float*)d_in[9];
    const float* b2       = (const float*)d_in[10];
    const float* w_attn   = (const float*)d_in[11];
    const float* b_attn   = (const float*)d_in[12];
    const float* w_mask   = (const float*)d_in[13];
    const float* b_mask   = (const float*)d_in[14];
    const float* W_out    = (const float*)d_in[15];
    const float* b_out    = (const float*)d_in[16];
    float* out = (float*)d_out;

    int N = in_sizes[0] / 128;
    int E = in_sizes[1] / 2;
    const int* esrc = edge_index;
    const int* edst = edge_index + E;

    char* ws = (char*)d_ws;
    size_t off = 0;
    auto alloc = [&](size_t bytes) {
        void* p = ws + off;
        off = (off + bytes + 255) & ~(size_t)255;
        return p;
    };
    ushort* h1       = (ushort*)alloc((size_t)N * 512 * 2);   // bf16
    ushort* r1       = (ushort*)alloc((size_t)N * 512 * 2);   // bf16
    ushort* h2       = (ushort*)alloc((size_t)N * 128 * 2);   // bf16
    float*  r2       = (float*)alloc((size_t)N * 128 * 4);
    float*  a1s      = (float*)alloc((size_t)N * 8 * 4);
    float*  a1d      = (float*)alloc((size_t)N * 8 * 4);
    float*  a2s      = (float*)alloc((size_t)N * 4);
    float*  a2d      = (float*)alloc((size_t)N * 4);
    int*    row_start= (int*)alloc((size_t)(N + 1) * 4);
    int*    cursor   = (int*)alloc((size_t)N * 4);
    int*    srcs     = (int*)alloc((size_t)E * 4);
    float*  pooled   = (float*)alloc((size_t)256 * 128 * 4);

    hipMemsetAsync(cursor, 0, (size_t)N * 4, stream);
    hipMemsetAsync(pooled, 0, 256 * 128 * 4, stream);

    dim3 b256(256);
    gemm_nt<float><<<dim3((N + 63) / 64, 512 / 64), b256, 0, stream>>>(x, W1, h1, N, 512, 128);
    scores1<<<(N + 3) / 4, b256, 0, stream>>>(h1, att_src1, att_dst1, a1s, a1d, N);
    count_edges<<<(E + 255) / 256, b256, 0, stream>>>(edst, cursor, E);
    scan_offsets<<<1, 1024, 0, stream>>>(cursor, row_start, cursor, N);
    fill_edges<<<(E + 255) / 256, b256, 0, stream>>>(esrc, edst, cursor, srcs, E);
    agg1<<<(N + 3) / 4, b256, 0, stream>>>(h1, a1s, a1d, row_start, srcs, b1, r1, N);
    gemm_nt<ushort><<<dim3((N + 63) / 64, 128 / 64), b256, 0, stream>>>(r1, W2, h2, N, 128, 512);
    scores2<<<(N + 3) / 4, b256, 0, stream>>>(h2, att_src2, att_dst2, a2s, a2d, N);
    agg2<<<(N + 7) / 8, b256, 0, stream>>>(h2, a2s, a2d, row_start, srcs, b2, r2, N);
    pool_kernel<<<(N + 3) / 4, b256, 0, stream>>>(r2, batch, w_attn, b_attn, w_mask,
                                                  b_mask, pooled, N);
    final_kernel<<<2, b256, 0, stream>>>(pooled, W_out, b_out, out);
}

// Round 3
// 316.436 us; speedup vs baseline: 1.4811x; 1.2461x over previous
//
#include <hip/hip_runtime.h>
#include <math.h>

// R2: MFMA bf16 GEMMs replace fp32 vector GEMMs (they were 88 us each at 19% of
// fp32 peak, latency/LDS-bound). x/W1/W2 cast to bf16; fp32 accumulate in AGPRs.
// Rest of pipeline unchanged from R1 (bf16 h1/r1/h2, single-pass softmax agg).

#define NEG_SLOPE 0.2f

using bf16x8 = __attribute__((ext_vector_type(8))) __bf16;
using f32x4  = __attribute__((ext_vector_type(4))) float;

// ---------- bf16 helpers (storage ushort, fp32 compute) ----------
__device__ __forceinline__ ushort f2bf(float f) {
    unsigned u = __float_as_uint(f);
    unsigned r = (u + 0x7FFFu + ((u >> 16) & 1u)) >> 16;   // RNE
    return (ushort)r;
}
__device__ __forceinline__ unsigned pack2(float a, float b) {
    return (unsigned)f2bf(a) | ((unsigned)f2bf(b) << 16);
}
__device__ __forceinline__ void unpack8(uint4 u, float* f) {
    f[0] = __uint_as_float(u.x << 16); f[1] = __uint_as_float(u.x & 0xFFFF0000u);
    f[2] = __uint_as_float(u.y << 16); f[3] = __uint_as_float(u.y & 0xFFFF0000u);
    f[4] = __uint_as_float(u.z << 16); f[5] = __uint_as_float(u.z & 0xFFFF0000u);
    f[6] = __uint_as_float(u.w << 16); f[7] = __uint_as_float(u.w & 0xFFFF0000u);
}
__device__ __forceinline__ void unpack4(uint2 u, float* f) {
    f[0] = __uint_as_float(u.x << 16); f[1] = __uint_as_float(u.x & 0xFFFF0000u);
    f[2] = __uint_as_float(u.y << 16); f[3] = __uint_as_float(u.y & 0xFFFF0000u);
}

// ---------------- fp32 -> bf16 convert (n % 4 == 0) ----------------
__global__ __launch_bounds__(256) void cvt_bf16(const float* __restrict__ in,
                                                ushort* __restrict__ out, int n4) {
    int i = blockIdx.x * 256 + threadIdx.x;
    if (i >= n4) return;
    float4 v = ((const float4*)in)[i];
    uint2 o;
    o.x = pack2(v.x, v.y);
    o.y = pack2(v.z, v.w);
    ((uint2*)out)[i] = o;
}

// ---------------- MFMA GEMM: C[M,N] = A[M,K] * B[N,K]^T (all bf16, fp32 acc) ----
// 128x128 tile, 256 threads (4 waves), each wave a 64x64 quadrant = 4x4 grid of
// 16x16x32 MFMAs. BK=32. LDS rows stride 40 bf16 (80 B): 16B-aligned, 2-way max
// bank aliasing (free). Requires N % 128 == 0, K % 32 == 0; M guarded.
#define LDSB 40
__global__ __launch_bounds__(256) void gemm_mfma(const ushort* __restrict__ A,
                                                 const ushort* __restrict__ B,
                                                 ushort* __restrict__ C,
                                                 int M, int N, int K) {
    __shared__ ushort As[128 * LDSB];
    __shared__ ushort Bs[128 * LDSB];
    int t = threadIdx.x;
    int wave = t >> 6, lane = t & 63;
    int quad = lane >> 4, l16 = lane & 15;
    int m0 = blockIdx.x * 128;
    int n0 = blockIdx.y * 128;
    int wm = (wave & 1) * 64;
    int wn = (wave >> 1) * 64;
    // staging: thread t loads 32 B of row (t>>1), segment (t&1)
    int srow = t >> 1;
    int sseg = (t & 1) * 16;          // element offset (16 bf16 = 32 B)
    f32x4 acc[4][4] = {};             // [mi][nj]
    for (int k0 = 0; k0 < K; k0 += 32) {
        uint4 av0, av1, bv0, bv1;
        {
            int grow = m0 + srow;
            if (grow < M) {
                const uint4* gp = (const uint4*)(A + (size_t)grow * K + k0 + sseg);
                av0 = gp[0]; av1 = gp[1];
            } else {
                av0 = make_uint4(0, 0, 0, 0); av1 = av0;
            }
            const uint4* gq = (const uint4*)(B + (size_t)(n0 + srow) * K + k0 + sseg);
            bv0 = gq[0]; bv1 = gq[1];
        }
        __syncthreads();   // previous chunk's LDS readers done
        *(uint4*)&As[srow * LDSB + sseg]     = av0;
        *(uint4*)&As[srow * LDSB + sseg + 8] = av1;
        *(uint4*)&Bs[srow * LDSB + sseg]     = bv0;
        *(uint4*)&Bs[srow * LDSB + sseg + 8] = bv1;
        __syncthreads();
        bf16x8 af[4], bf[4];
#pragma unroll
        for (int i = 0; i < 4; ++i)
            af[i] = *(const bf16x8*)&As[(wm + i * 16 + l16) * LDSB + quad * 8];
#pragma unroll
        for (int j = 0; j < 4; ++j)
            bf[j] = *(const bf16x8*)&Bs[(wn + j * 16 + l16) * LDSB + quad * 8];
#pragma unroll
        for (int i = 0; i < 4; ++i)
#pragma unroll
            for (int j = 0; j < 4; ++j)
                acc[i][j] = __builtin_amdgcn_mfma_f32_16x16x32_bf16(
                    af[i], bf[j], acc[i][j], 0, 0, 0);
    }
    // epilogue: C/D layout col=lane&15, row=quad*4+reg
#pragma unroll
    for (int i = 0; i < 4; ++i) {
#pragma unroll
        for (int r = 0; r < 4; ++r) {
            int grow = m0 + wm + i * 16 + quad * 4 + r;
            if (grow < M) {
#pragma unroll
                for (int j = 0; j < 4; ++j) {
                    int gcol = n0 + wn + j * 16 + l16;
                    C[(size_t)grow * N + gcol] = f2bf(acc[i][j][r]);
                }
            }
        }
    }
}

// ---------------- Layer-1 attention scores: a1s/a1d [N,8], h1 bf16 ----------------
__global__ __launch_bounds__(256) void scores1(const ushort* __restrict__ h1,
                                               const float* __restrict__ att_s,
                                               const float* __restrict__ att_d,
                                               float* __restrict__ a1s,
                                               float* __restrict__ a1d, int N) {
    int node = blockIdx.x * 4 + (threadIdx.x >> 6);
    if (node >= N) return;
    int lane = threadIdx.x & 63;
    uint4 u = *(const uint4*)(h1 + (size_t)node * 512 + lane * 8);
    float h[8];
    unpack8(u, h);
    const float4* sp = (const float4*)(att_s + lane * 8);
    const float4* dp = (const float4*)(att_d + lane * 8);
    float4 s0 = sp[0], s1 = sp[1], d0 = dp[0], d1 = dp[1];
    float ps = h[0] * s0.x + h[1] * s0.y + h[2] * s0.z + h[3] * s0.w +
               h[4] * s1.x + h[5] * s1.y + h[6] * s1.z + h[7] * s1.w;
    float pd = h[0] * d0.x + h[1] * d0.y + h[2] * d0.z + h[3] * d0.w +
               h[4] * d1.x + h[5] * d1.y + h[6] * d1.z + h[7] * d1.w;
#pragma unroll
    for (int off = 1; off < 8; off <<= 1) {
        ps += __shfl_xor(ps, off);
        pd += __shfl_xor(pd, off);
    }
    if ((lane & 7) == 0) {
        a1s[node * 8 + (lane >> 3)] = ps;
        a1d[node * 8 + (lane >> 3)] = pd;
    }
}

// ---------------- CSR build ----------------
__global__ void count_edges(const int* __restrict__ dst, int* cnt, int E) {
    int e = blockIdx.x * 256 + threadIdx.x;
    if (e < E) atomicAdd(&cnt[dst[e]], 1);
}

__global__ __launch_bounds__(1024) void scan_offsets(const int* cnt, int* row_start,
                                                     int* cursor, int N) {
    __shared__ int sm[1024];
    int t = threadIdx.x;
    int per = (N + 1023) / 1024;
    int beg = t * per;
    int end = beg + per; if (end > N) end = N;
    int sum = 0;
    for (int i = beg; i < end; ++i) sum += cnt[i];
    sm[t] = sum;
    __syncthreads();
    for (int off = 1; off < 1024; off <<= 1) {
        int add = (t >= off) ? sm[t - off] : 0;
        __syncthreads();
        sm[t] += add;
        __syncthreads();
    }
    int run = sm[t] - sum;
    for (int i = beg; i < end; ++i) {
        int c = cnt[i];
        row_start[i] = run;
        cursor[i] = run;
        run += c;
    }
    if (t == 1023) row_start[N] = run;
}

__global__ void fill_edges(const int* __restrict__ src, const int* __restrict__ dst,
                           int* cursor, int* __restrict__ srcs, int E) {
    int e = blockIdx.x * 256 + threadIdx.x;
    if (e < E) {
        int pos = atomicAdd(&cursor[dst[e]], 1);
        srcs[pos] = src[e];
    }
}

// ---------------- Layer-1 single-pass softmax-aggregate + bias + relu ----------------
__global__ __launch_bounds__(256) void agg1(const ushort* __restrict__ h1,
                                            const float* __restrict__ a1s,
                                            const float* __restrict__ a1d,
                                            const int* __restrict__ row_start,
                                            const int* __restrict__ srcs,
                                            const float* __restrict__ b1,
                                            ushort* __restrict__ r1, int N) {
    int node = blockIdx.x * 4 + (threadIdx.x >> 6);
    if (node >= N) return;
    int lane = threadIdx.x & 63;
    int head = lane >> 3;
    int f0 = lane * 8;
    int pbeg = row_start[node], pend = row_start[node + 1];
    float ad = a1d[node * 8 + head];
    float es = a1s[node * 8 + head] + ad;
    es = es > 0.f ? es : NEG_SLOPE * es;
    float ex_self = __expf(es);
    float den = ex_self;
    float q[8];
    unpack8(*(const uint4*)(h1 + (size_t)node * 512 + f0), q);
    float acc[8];
#pragma unroll
    for (int j = 0; j < 8; ++j) acc[j] = ex_self * q[j];
    for (int p = pbeg; p < pend; ++p) {
        int s = srcs[p];
        float e = a1s[s * 8 + head] + ad;
        e = e > 0.f ? e : NEG_SLOPE * e;
        float ex = __expf(e);
        den += ex;
        float v[8];
        unpack8(*(const uint4*)(h1 + (size_t)s * 512 + f0), v);
#pragma unroll
        for (int j = 0; j < 8; ++j) acc[j] += ex * v[j];
    }
    float rden = 1.0f / (den + 1e-16f);
    const float4* bp = (const float4*)(b1 + f0);
    float4 b0 = bp[0], b1v = bp[1];
    float o[8];
    o[0] = fmaxf(acc[0] * rden + b0.x, 0.f);
    o[1] = fmaxf(acc[1] * rden + b0.y, 0.f);
    o[2] = fmaxf(acc[2] * rden + b0.z, 0.f);
    o[3] = fmaxf(acc[3] * rden + b0.w, 0.f);
    o[4] = fmaxf(acc[4] * rden + b1v.x, 0.f);
    o[5] = fmaxf(acc[5] * rden + b1v.y, 0.f);
    o[6] = fmaxf(acc[6] * rden + b1v.z, 0.f);
    o[7] = fmaxf(acc[7] * rden + b1v.w, 0.f);
    uint4 ov;
    ov.x = pack2(o[0], o[1]); ov.y = pack2(o[2], o[3]);
    ov.z = pack2(o[4], o[5]); ov.w = pack2(o[6], o[7]);
    *(uint4*)(r1 + (size_t)node * 512 + f0) = ov;
}

// ---------------- Layer-2 attention scores (H=1, C=128), h2 bf16 ----------------
__global__ __launch_bounds__(256) void scores2(const ushort* __restrict__ h2,
                                               const float* __restrict__ att_s,
                                               const float* __restrict__ att_d,
                                               float* __restrict__ a2s,
                                               float* __restrict__ a2d, int N) {
    int node = blockIdx.x * 4 + (threadIdx.x >> 6);
    if (node >= N) return;
    int lane = threadIdx.x & 63;
    unsigned u = *(const unsigned*)(h2 + (size_t)node * 128 + lane * 2);
    float h0 = __uint_as_float(u << 16), h1v = __uint_as_float(u & 0xFFFF0000u);
    float2 s = *(const float2*)(att_s + lane * 2);
    float2 d = *(const float2*)(att_d + lane * 2);
    float ps = h0 * s.x + h1v * s.y;
    float pd = h0 * d.x + h1v * d.y;
#pragma unroll
    for (int off = 1; off < 64; off <<= 1) {
        ps += __shfl_xor(ps, off);
        pd += __shfl_xor(pd, off);
    }
    if (lane == 0) { a2s[node] = ps; a2d[node] = pd; }
}

// ---------------- Layer-2 single-pass aggregate: 2 nodes per wave ----------------
__global__ __launch_bounds__(256) void agg2(const ushort* __restrict__ h2,
                                            const float* __restrict__ a2s,
                                            const float* __restrict__ a2d,
                                            const int* __restrict__ row_start,
                                            const int* __restrict__ srcs,
                                            const float* __restrict__ b2,
                                            float* __restrict__ r2, int N) {
    int node = blockIdx.x * 8 + (threadIdx.x >> 5);
    if (node >= N) return;
    int sub = threadIdx.x & 31;
    int f0 = sub * 4;
    int pbeg = row_start[node], pend = row_start[node + 1];
    float ad = a2d[node];
    float es = a2s[node] + ad;
    es = es > 0.f ? es : NEG_SLOPE * es;
    float ex_self = __expf(es);
    float den = ex_self;
    float q[4];
    unpack4(*(const uint2*)(h2 + (size_t)node * 128 + f0), q);
    float acc[4];
#pragma unroll
    for (int j = 0; j < 4; ++j) acc[j] = ex_self * q[j];
    for (int p = pbeg; p < pend; ++p) {
        int s = srcs[p];
        float e = a2s[s] + ad;
        e = e > 0.f ? e : NEG_SLOPE * e;
        float ex = __expf(e);
        den += ex;
        float v[4];
        unpack4(*(const uint2*)(h2 + (size_t)s * 128 + f0), v);
#pragma unroll
        for (int j = 0; j < 4; ++j) acc[j] += ex * v[j];
    }
    float rden = 1.0f / (den + 1e-16f);
    float4 bv = *(const float4*)(b2 + f0);
    float4 o;
    o.x = fmaxf(acc[0] * rden + bv.x, 0.f);
    o.y = fmaxf(acc[1] * rden + bv.y, 0.f);
    o.z = fmaxf(acc[2] * rden + bv.z, 0.f);
    o.w = fmaxf(acc[3] * rden + bv.w, 0.f);
    *(float4*)(r2 + (size_t)node * 128 + f0) = o;
}

// ---------------- Attention pooling ----------------
__global__ __launch_bounds__(256) void pool_kernel(const float* __restrict__ r2,
                                                   const int* __restrict__ batch,
                                                   const float* __restrict__ w_attn,
                                                   const float* __restrict__ b_attn,
                                                   const float* __restrict__ w_mask,
                                                   const float* __restrict__ b_mask,
                                                   float* pooled, int N) {
    int node = blockIdx.x * 4 + (threadIdx.x >> 6);
    if (node >= N) return;
    int lane = threadIdx.x & 63;
    float2 h = *(const float2*)(r2 + (size_t)node * 128 + lane * 2);
    float2 wa = *(const float2*)(w_attn + lane * 2);
    float2 wm = *(const float2*)(w_mask + lane * 2);
    float pa = h.x * wa.x + h.y * wa.y;
    float pm = h.x * wm.x + h.y * wm.y;
#pragma unroll
    for (int off = 1; off < 64; off <<= 1) {
        pa += __shfl_xor(pa, off);
        pm += __shfl_xor(pm, off);
    }
    float attn = pa + b_attn[0];
    float mask = 1.0f / (1.0f + __expf(-(pm + b_mask[0])));
    float w = attn * mask;
    int g = batch[node];
    atomicAdd(&pooled[g * 128 + lane * 2], h.x * w);
    atomicAdd(&pooled[g * 128 + lane * 2 + 1], h.y * w);
}

// ---------------- Final tiny GEMM: out[256,2] ----------------
__global__ void final_kernel(const float* __restrict__ pooled,
                             const float* __restrict__ W_out,
                             const float* __restrict__ b_out,
                             float* __restrict__ out) {
    int tid = blockIdx.x * 256 + threadIdx.x;
    if (tid >= 512) return;
    int g = tid >> 1, o = tid & 1;
    const float* p = pooled + g * 128;
    const float* w = W_out + o * 128;
    float s = 0.f;
#pragma unroll 4
    for (int f = 0; f < 128; ++f) s += p[f] * w[f];
    out[tid] = s + b_out[o];
}

extern "C" void kernel_launch(void* const* d_in, const int* in_sizes, int n_in,
                              void* d_out, int out_size, void* d_ws, size_t ws_size,
                              hipStream_t stream) {
    const float* x        = (const float*)d_in[0];
    const int* edge_index = (const int*)d_in[1];
    const int* batch      = (const int*)d_in[2];
    const float* W1       = (const float*)d_in[3];
    const float* att_src1 = (const float*)d_in[4];
    const float* att_dst1 = (const float*)d_in[5];
    const float* b1       = (const float*)d_in[6];
    const float* W2       = (const float*)d_in[7];
    const float* att_src2 = (const float*)d_in[8];
    const float* att_dst2 = (const float*)d_in[9];
    const float* b2       = (const float*)d_in[10];
    const float* w_attn   = (const float*)d_in[11];
    const float* b_attn   = (const float*)d_in[12];
    const float* w_mask   = (const float*)d_in[13];
    const float* b_mask   = (const float*)d_in[14];
    const float* W_out    = (const float*)d_in[15];
    const float* b_out    = (const float*)d_in[16];
    float* out = (float*)d_out;

    int N = in_sizes[0] / 128;
    int E = in_sizes[1] / 2;
    const int* esrc = edge_index;
    const int* edst = edge_index + E;

    char* ws = (char*)d_ws;
    size_t off = 0;
    auto alloc = [&](size_t bytes) {
        void* p = ws + off;
        off = (off + bytes + 255) & ~(size_t)255;
        return p;
    };
    ushort* h1       = (ushort*)alloc((size_t)N * 512 * 2);   // bf16
    ushort* r1       = (ushort*)alloc((size_t)N * 512 * 2);   // bf16
    ushort* h2       = (ushort*)alloc((size_t)N * 128 * 2);   // bf16
    float*  r2       = (float*)alloc((size_t)N * 128 * 4);
    ushort* xb       = (ushort*)alloc((size_t)N * 128 * 2);   // bf16 x
    ushort* w1b      = (ushort*)alloc((size_t)512 * 128 * 2);
    ushort* w2b      = (ushort*)alloc((size_t)128 * 512 * 2);
    float*  a1s      = (float*)alloc((size_t)N * 8 * 4);
    float*  a1d      = (float*)alloc((size_t)N * 8 * 4);
    float*  a2s      = (float*)alloc((size_t)N * 4);
    float*  a2d      = (float*)alloc((size_t)N * 4);
    int*    row_start= (int*)alloc((size_t)(N + 1) * 4);
    int*    cursor   = (int*)alloc((size_t)N * 4);
    int*    srcs     = (int*)alloc((size_t)E * 4);
    float*  pooled   = (float*)alloc((size_t)256 * 128 * 4);

    hipMemsetAsync(cursor, 0, (size_t)N * 4, stream);
    hipMemsetAsync(pooled, 0, 256 * 128 * 4, stream);

    dim3 b256(256);
    // converts
    int nx4 = N * 128 / 4;
    cvt_bf16<<<(nx4 + 255) / 256, b256, 0, stream>>>(x, xb, nx4);
    cvt_bf16<<<(512 * 128 / 4 + 255) / 256, b256, 0, stream>>>(W1, w1b, 512 * 128 / 4);
    cvt_bf16<<<(128 * 512 / 4 + 255) / 256, b256, 0, stream>>>(W2, w2b, 128 * 512 / 4);
    // CSR build (independent of GEMM1)
    count_edges<<<(E + 255) / 256, b256, 0, stream>>>(edst, cursor, E);
    scan_offsets<<<1, 1024, 0, stream>>>(cursor, row_start, cursor, N);
    fill_edges<<<(E + 255) / 256, b256, 0, stream>>>(esrc, edst, cursor, srcs, E);
    // layer 1
    gemm_mfma<<<dim3((N + 127) / 128, 512 / 128), b256, 0, stream>>>(xb, w1b, h1, N, 512, 128);
    scores1<<<(N + 3) / 4, b256, 0, stream>>>(h1, att_src1, att_dst1, a1s, a1d, N);
    agg1<<<(N + 3) / 4, b256, 0, stream>>>(h1, a1s, a1d, row_start, srcs, b1, r1, N);
    // layer 2
    gemm_mfma<<<dim3((N + 127) / 128, 128 / 128), b256, 0, stream>>>(r1, w2b, h2, N, 128, 512);
    scores2<<<(N + 3) / 4, b256, 0, stream>>>(h2, att_src2, att_dst2, a2s, a2d, N);
    agg2<<<(N + 7) / 8, b256, 0, stream>>>(h2, a2s, a2d, row_start, srcs, b2, r2, N);
    // pooling + head
    pool_kernel<<<(N + 3) / 4, b256, 0, stream>>>(r2, batch, w_attn, b_attn, w_mask,
                                                  b_mask, pooled, N);
    final_kernel<<<2, b256, 0, stream>>>(pooled, W_out, b_out, out);
}